// Round 8
// baseline (346.485 us; speedup 1.0000x reference)
//
#include <hip/hip_runtime.h>

#define DIM   1024
#define LPR   32            // lanes cooperating on one row (2 rows per wave)
#define SEG   (DIM / LPR)   // 32 floats per lane
#define SEG4  (SEG / 4)     // 8 float4 per lane
#define WAVES_PER_BLOCK 4
#define PAIRS_PER_WAVE  4   // row-pairs each wave streams through

typedef float f32x4 __attribute__((ext_vector_type(4)));
#define AS1 __attribute__((address_space(1)))
#define AS3 __attribute__((address_space(3)))

// ---------------- kernel 1: permuted cos/sin table -> d_ws ------------------
// ws[loc] = (cos a_j, sin a_j), loc = (j&31)*32 + (j>>5) (10-bit rot5), so the
// main kernel's phase read cs[i*32+t] is linear-in-t (2-way max = free).
__global__ void qll_table(const float* __restrict__ angles, float2* __restrict__ ws) {
    int j = blockIdx.x * blockDim.x + threadIdx.x;
    if (j < DIM) {
        float a = angles[j];
        ws[(j & 31) * LPR + (j >> 5)] = make_float2(cosf(a), sinf(a));
    }
}

// ---------------- main kernel ----------------------------------------------
// Row recurrence (Givens sweep): carry = value of column i entering step i.
//   out[i] = c_i*carry - s_i*v[i+1];  carry' = s_i*carry + c_i*v[i+1]
// Affine in carry -> per-lane (A,B) + width-32 shfl scan (the wave's two rows
// scan in parallel).
//
// vs r7: each wave STREAMS PAIRS_PER_WAVE row-pairs with register prefetch
// (coalesced global_load_dwordx4 -> 32 VGPRs -> ds_write swizzled). Loads for
// pair k+1 fly during compute of pair k, so the HBM latency stall is paid
// once per wave, not once per pair. LDS layout & compute identical to r7:
// LDS[m*64+i] = G[m*64 + p(i)], p(i)=i^((i>>3)&7) (involution), so segment
// reads use index e^(t&7) as before. One barrier per block (cs table only).
__global__ __launch_bounds__(256, 4)
void qll_kernel(const float* __restrict__ x,
                const float2* __restrict__ csws,
                float* __restrict__ out,
                int batch)
{
    __shared__ float2 cs[DIM];                      // 8 KB
    __shared__ f32x4  stage[WAVES_PER_BLOCK][512];  // 32 KB, wave-private

    const int tid  = threadIdx.x;
    const int l    = tid & 63;        // lane in wave
    const int wave = tid >> 6;        // 0..3
    const int h    = (tid >> 5) & 1;  // which row of the pair
    const int t    = tid & 31;        // segment index within row
    const int swz_l = l ^ ((l >> 3) & 7);           // involution on f32x4 index

    // ---- prologue: cs table via 2 glds (L2-resident), one __syncthreads ----
    const f32x4* w4 = reinterpret_cast<const f32x4*>(csws);
    f32x4* c4 = reinterpret_cast<f32x4*>(cs);
    __builtin_amdgcn_global_load_lds((const AS1 void*)(w4 + wave * 64 + l),
                                     (AS3 void*)(c4 + wave * 64), 16, 0, 0);
    __builtin_amdgcn_global_load_lds((const AS1 void*)(w4 + 256 + wave * 64 + l),
                                     (AS3 void*)(c4 + 256 + wave * 64), 16, 0, 0);
    __syncthreads();   // drains the 2 glds (vmcnt(0)) + barrier; only barrier in kernel

    // ---- this wave's streak of row-pairs ----
    const int pairBase = (blockIdx.x * WAVES_PER_BLOCK + wave) * PAIRS_PER_WAVE;
    const int pairsTot = batch >> 1;
    int np = pairsTot - pairBase;
    if (np <= 0) return;
    if (np > PAIRS_PER_WAVE) np = PAIRS_PER_WAVE;

    const f32x4* ginb = reinterpret_cast<const f32x4*>(x);
    f32x4*       goutb = reinterpret_cast<f32x4*>(out);

    // prefetch pair 0 into registers (coalesced: lane l takes chunk m*64+l)
    f32x4 pf[8];
    {
        const f32x4* g = ginb + (size_t)pairBase * 512;
#pragma unroll
        for (int m = 0; m < 8; ++m) pf[m] = g[m * 64 + l];
    }

    for (int it = 0; it < np; ++it) {
        // ---- in-stage: regs -> LDS at swizzled slot (LDS[m*64+p(l)]=G[m*64+l]) ----
#pragma unroll
        for (int m = 0; m < 8; ++m)
            stage[wave][m * 64 + swz_l] = pf[m];

        // ---- read this lane's 32-float segment (bank-balanced b128s) ----
        float v[SEG];
#pragma unroll
        for (int e = 0; e < SEG4; ++e) {
            f32x4 q = stage[wave][h * 256 + t * 8 + (e ^ (t & 7))];
            v[4*e+0] = q.x; v[4*e+1] = q.y; v[4*e+2] = q.z; v[4*e+3] = q.w;
        }

        // ---- issue prefetch for the NEXT pair; flies during compute ----
        if (it + 1 < np) {
            const f32x4* g = ginb + (size_t)(pairBase + it + 1) * 512;
#pragma unroll
            for (int m = 0; m < 8; ++m) pf[m] = g[m * 64 + l];
        }

        // boundary exchanges (capture BEFORE phase 2 overwrites v[])
        float v0row = __shfl(v[0], 0, LPR);        // row's original column 0
        float v1row = __shfl(v[1], 0, LPR);
        float vnext = __shfl_down(v[0], 1, LPR);   // next lane's first elem

        // ---- phase 1: per-lane affine (A,B) with carry_in = 0 ----
        float A = 1.f, B = 0.f;
#pragma unroll
        for (int i = 0; i < SEG - 1; ++i) {
            float2 w = cs[i * LPR + t];
            B = w.y * B + w.x * v[i + 1];
            A = w.y * A;
        }
        {   // last step of segment consumes the boundary element
            float2 w = cs[(SEG - 1) * LPR + t];
            B = w.y * B + w.x * vnext;   // lane 31: finite garbage, unused
            A = w.y * A;
        }

        // ---- inclusive affine scan across 32 lanes (both rows in parallel) ----
#pragma unroll
        for (int d = 1; d < LPR; d <<= 1) {
            float pa = __shfl_up(A, d, LPR);
            float pb = __shfl_up(B, d, LPR);
            if (t >= d) { B = A * pb + B; A = A * pa; }
        }
        // exclusive prefix -> carry entering this lane's segment
        float ea = __shfl_up(A, 1, LPR);
        float eb = __shfl_up(B, 1, LPR);
        if (t == 0) { ea = 1.f; eb = 0.f; }
        float carry = ea * v0row + eb;

        // provisional out[0] (result of step 0), consumed by wrap step 1023
        float2 w0 = cs[0];
        float out0_prov = w0.x * v0row - w0.y * v1row;

        // ---- phase 2: replay with true carry, outputs into v[] ----
#pragma unroll
        for (int i = 0; i < SEG - 1; ++i) {
            float2 w = cs[i * LPR + t];
            float vn = v[i + 1];
            float o  = w.x * carry - w.y * vn;
            carry    = w.y * carry + w.x * vn;
            v[i] = o;
        }
        {   // last step; lane 31 executes the wrap step 1023 against out[0]
            float2 w  = cs[(SEG - 1) * LPR + t];
            float vn  = (t == LPR - 1) ? out0_prov : vnext;
            float o   = w.x * carry - w.y * vn;
            float nc  = w.y * carry + w.x * vn;
            v[SEG - 1] = o;
            float out0_final = __shfl(nc, LPR - 1, LPR);  // lane 31 -> all
            if (t == 0) v[0] = out0_final;
        }

        // ---- out-stage into the same buffer (same-wave DS pipe is in-order:
        //      these writes land after the segment reads above), then
        //      coalesced nontemporal stores ----
#pragma unroll
        for (int e = 0; e < SEG4; ++e) {
            f32x4 q = { v[4*e+0], v[4*e+1], v[4*e+2], v[4*e+3] };
            stage[wave][h * 256 + t * 8 + (e ^ (t & 7))] = q;
        }
        f32x4* gout = goutb + (size_t)(pairBase + it) * 512;
#pragma unroll
        for (int m = 0; m < 8; ++m) {
            f32x4 q = stage[wave][m * 64 + swz_l];
            __builtin_nontemporal_store(q, gout + m * 64 + l);
        }
    }
}

// ---------------- fallback (ws too small): r6-style self-contained ---------
__global__ __launch_bounds__(256, 4)
void qll_kernel_fb(const float* __restrict__ x,
                   const float* __restrict__ angles,
                   float* __restrict__ out,
                   int batch)
{
    __shared__ float2 cs[DIM];
    __shared__ f32x4  stage[WAVES_PER_BLOCK][512];

    const int tid  = threadIdx.x;
    const int l    = tid & 63;
    const int wave = tid >> 6;
    const int h    = (tid >> 5) & 1;
    const int t    = tid & 31;
    const int r0   = blockIdx.x * (WAVES_PER_BLOCK * 2) + wave * 2;
    const bool active = (r0 + 2 <= batch);
    const int swz_l = l ^ ((l >> 3) & 7);

    for (int loc = tid; loc < DIM; loc += 256) {
        int j = ((loc & 31) << 5) | (loc >> 5);
        float a = angles[j];
        cs[loc] = make_float2(cosf(a), sinf(a));
    }
    __syncthreads();
    if (!active) return;

    const f32x4* gin = reinterpret_cast<const f32x4*>(x) + (size_t)r0 * 256;
#pragma unroll
    for (int m = 0; m < 8; ++m) {
        __builtin_amdgcn_global_load_lds(
            (const AS1 void*)(gin + m * 64 + swz_l),
            (AS3 void*)(&stage[wave][m * 64]), 16, 0, 0);
    }
    asm volatile("s_waitcnt vmcnt(0)" ::: "memory");
    __builtin_amdgcn_sched_barrier(0);

    float v[SEG];
#pragma unroll
    for (int e = 0; e < SEG4; ++e) {
        f32x4 q = stage[wave][h * 256 + t * 8 + (e ^ (t & 7))];
        v[4*e+0] = q.x; v[4*e+1] = q.y; v[4*e+2] = q.z; v[4*e+3] = q.w;
    }
    float v0row = __shfl(v[0], 0, LPR);
    float v1row = __shfl(v[1], 0, LPR);
    float vnext = __shfl_down(v[0], 1, LPR);

    float A = 1.f, B = 0.f;
#pragma unroll
    for (int i = 0; i < SEG - 1; ++i) {
        float2 w = cs[i * LPR + t];
        B = w.y * B + w.x * v[i + 1];
        A = w.y * A;
    }
    {
        float2 w = cs[(SEG - 1) * LPR + t];
        B = w.y * B + w.x * vnext;
        A = w.y * A;
    }
#pragma unroll
    for (int d = 1; d < LPR; d <<= 1) {
        float pa = __shfl_up(A, d, LPR);
        float pb = __shfl_up(B, d, LPR);
        if (t >= d) { B = A * pb + B; A = A * pa; }
    }
    float ea = __shfl_up(A, 1, LPR);
    float eb = __shfl_up(B, 1, LPR);
    if (t == 0) { ea = 1.f; eb = 0.f; }
    float carry = ea * v0row + eb;

    float2 w0 = cs[0];
    float out0_prov = w0.x * v0row - w0.y * v1row;

#pragma unroll
    for (int i = 0; i < SEG - 1; ++i) {
        float2 w = cs[i * LPR + t];
        float vn = v[i + 1];
        float o  = w.x * carry - w.y * vn;
        carry    = w.y * carry + w.x * vn;
        v[i] = o;
    }
    {
        float2 w  = cs[(SEG - 1) * LPR + t];
        float vn  = (t == LPR - 1) ? out0_prov : vnext;
        float o   = w.x * carry - w.y * vn;
        float nc  = w.y * carry + w.x * vn;
        v[SEG - 1] = o;
        float out0_final = __shfl(nc, LPR - 1, LPR);
        if (t == 0) v[0] = out0_final;
    }
#pragma unroll
    for (int e = 0; e < SEG4; ++e) {
        f32x4 q = { v[4*e+0], v[4*e+1], v[4*e+2], v[4*e+3] };
        stage[wave][h * 256 + t * 8 + (e ^ (t & 7))] = q;
    }
    f32x4* gout = reinterpret_cast<f32x4*>(out) + (size_t)r0 * 256;
#pragma unroll
    for (int m = 0; m < 8; ++m) {
        f32x4 q = stage[wave][m * 64 + swz_l];
        __builtin_nontemporal_store(q, gout + m * 64 + l);
    }
}

extern "C" void kernel_launch(void* const* d_in, const int* in_sizes, int n_in,
                              void* d_out, int out_size, void* d_ws, size_t ws_size,
                              hipStream_t stream) {
    const float* x      = (const float*)d_in[0];
    const float* angles = (const float*)d_in[1];
    float* outp         = (float*)d_out;

    int batch = in_sizes[0] / DIM;   // 65536

    if (ws_size >= (size_t)(DIM * sizeof(float2))) {
        float2* ws = (float2*)d_ws;
        qll_table<<<(DIM + 255) / 256, 256, 0, stream>>>(angles, ws);
        int pairs = batch / 2;                                   // 32768
        int pairsPerBlock = WAVES_PER_BLOCK * PAIRS_PER_WAVE;    // 16
        int grid = (pairs + pairsPerBlock - 1) / pairsPerBlock;  // 2048
        qll_kernel<<<grid, 256, 0, stream>>>(x, ws, outp, batch);
    } else {
        int rowsPerBlock = WAVES_PER_BLOCK * 2;
        int grid = (batch + rowsPerBlock - 1) / rowsPerBlock;
        qll_kernel_fb<<<grid, 256, 0, stream>>>(x, angles, outp, batch);
    }
}

// Round 9
// 112.048 us; speedup vs baseline: 3.0923x; 3.0923x over previous
//
#include <hip/hip_runtime.h>

#define DIM   1024
#define LPR   32            // lanes cooperating on one row (2 rows per wave)
#define SEG   (DIM / LPR)   // 32 floats per lane
#define SEG4  (SEG / 4)     // 8 float4 per lane
#define WAVES_PER_BLOCK 4

typedef float f32x4 __attribute__((ext_vector_type(4)));
#define AS1 __attribute__((address_space(1)))
#define AS3 __attribute__((address_space(3)))

// ---------------- kernel 1: cos/sin table -> d_ws (NATURAL order) ----------
// ws[j] = (cos a_j, sin a_j). Lane t's steps are j = t*32+i (contiguous), so
// the main kernel streams its slice as float4 directly from global (L1-hot).
__global__ void qll_table(const float* __restrict__ angles, float2* __restrict__ ws) {
    int j = blockIdx.x * blockDim.x + threadIdx.x;
    if (j < DIM) {
        float a = angles[j];
        ws[j] = make_float2(cosf(a), sinf(a));
    }
}

// ---------------- main kernel ----------------------------------------------
// Row recurrence (Givens sweep): carry = value of column i entering step i.
//   out[i] = c_i*carry - s_i*v[i+1];  carry' = s_i*carry + c_i*v[i+1]
// Affine in carry -> per-lane (A,B) + width-32 shfl scan (the wave's two rows
// scan in parallel).
//
// vs r7 — DS-pipe diet (r7: ~900 DS cyc/wave, ~48us/CU serialized):
//  * cs table: streamed from GLOBAL (8KB, L1-resident) as float4, 2 steps per
//    load. Removes 64 ds_read_b64/wave, the LDS cs buffer, and ALL barriers.
//  * v segment: loaded DIRECTLY from global (lane-contiguous 128B, 8xdwordx4);
//    lines fully consumed within the wave -> HBM traffic stays 1x.
//  * LDS used ONLY for the output transpose (proven clean 262MB writes).
// Live regs ~55 (v[32]+temps) — stays under the 64-VGPR wall (r5/r8 spills).
__global__ __launch_bounds__(256)
void qll_kernel(const float* __restrict__ x,
                const float2* __restrict__ csws,
                float* __restrict__ out,
                int batch)
{
    __shared__ f32x4 stage[WAVES_PER_BLOCK][512];   // 32 KB, wave-private

    const int tid  = threadIdx.x;
    const int l    = tid & 63;        // lane in wave
    const int wave = tid >> 6;        // 0..3
    const int h    = (tid >> 5) & 1;  // which row of the pair
    const int t    = tid & 31;        // segment index within row
    const int r0   = (blockIdx.x * WAVES_PER_BLOCK + wave) * 2;
    if (r0 + 2 > batch) return;       // wave-uniform; no barriers below

    const int swz_l = l ^ ((l >> 3) & 7);           // involution on f32x4 index

    // ---- v segment: direct global loads, lane-contiguous 128B ----
    const f32x4* vin = reinterpret_cast<const f32x4*>(x)
                     + (size_t)(r0 + h) * 256 + t * 8;
    float v[SEG];
#pragma unroll
    for (int e = 0; e < SEG4; ++e) {
        f32x4 q = vin[e];
        v[4*e+0] = q.x; v[4*e+1] = q.y; v[4*e+2] = q.z; v[4*e+3] = q.w;
    }

    // boundary exchanges (capture BEFORE phase 2 overwrites v[])
    float v0row = __shfl(v[0], 0, LPR);        // row's original column 0
    float v1row = __shfl(v[1], 0, LPR);
    float vnext = __shfl_down(v[0], 1, LPR);   // next lane's first elem (t=31 unused)

    // lane t's cs slice: steps t*32..t*32+31 = 16 float4 (2 steps each)
    const f32x4* cs4 = reinterpret_cast<const f32x4*>(csws) + t * 16;

    // ---- phase 1: per-lane affine (A,B) with carry_in = 0 ----
    float A = 1.f, B = 0.f;
#pragma unroll
    for (int ii = 0; ii < 16; ++ii) {
        f32x4 q = cs4[ii];                      // (c,s) of steps 2ii, 2ii+1
        B = q.y * B + q.x * v[2*ii + 1];        // step 2ii
        A = q.y * A;
        float vn = (ii == 15) ? vnext : v[2*ii + 2];
        B = q.w * B + q.z * vn;                 // step 2ii+1 (lane 31 @ii=15: unused garbage)
        A = q.w * A;
    }

    // ---- inclusive affine scan across 32 lanes (both rows in parallel) ----
#pragma unroll
    for (int d = 1; d < LPR; d <<= 1) {
        float pa = __shfl_up(A, d, LPR);
        float pb = __shfl_up(B, d, LPR);
        if (t >= d) { B = A * pb + B; A = A * pa; }
    }
    // exclusive prefix -> carry entering this lane's segment
    float ea = __shfl_up(A, 1, LPR);
    float eb = __shfl_up(B, 1, LPR);
    if (t == 0) { ea = 1.f; eb = 0.f; }
    float carry = ea * v0row + eb;

    // provisional out[0] (result of step 0), consumed by the wrap step 1023
    float2 w0 = csws[0];                        // uniform load, L1
    float out0_prov = w0.x * v0row - w0.y * v1row;

    // ---- phase 2: replay with true carry, outputs into v[] ----
#pragma unroll
    for (int ii = 0; ii < 16; ++ii) {
        f32x4 q = cs4[ii];
        float vn0 = v[2*ii + 1];
        float o0  = q.x * carry - q.y * vn0;    // out[2ii]
        carry     = q.y * carry + q.x * vn0;
        v[2*ii] = o0;
        float vn1 = (ii == 15) ? ((t == LPR - 1) ? out0_prov : vnext)
                               : v[2*ii + 2];
        float o1  = q.z * carry - q.w * vn1;    // out[2ii+1]
        carry     = q.w * carry + q.z * vn1;    // lane31 @ii=15: final col-0 value
        v[2*ii + 1] = o1;
    }
    float out0_final = __shfl(carry, LPR - 1, LPR);  // lane 31 -> all
    if (t == 0) v[0] = out0_final;

    // ---- out-stage via LDS (same-wave DS pipe in-order; wave-private
    //      buffer, no barrier), then coalesced nontemporal stores ----
#pragma unroll
    for (int e = 0; e < SEG4; ++e) {
        f32x4 q = { v[4*e+0], v[4*e+1], v[4*e+2], v[4*e+3] };
        stage[wave][h * 256 + t * 8 + (e ^ (t & 7))] = q;
    }
    f32x4* gout = reinterpret_cast<f32x4*>(out) + (size_t)r0 * 256;
#pragma unroll
    for (int m = 0; m < 8; ++m) {
        f32x4 q = stage[wave][m * 64 + swz_l];
        __builtin_nontemporal_store(q, gout + m * 64 + l);
    }
}

// ---------------- fallback (ws too small): r6-style self-contained ---------
__global__ __launch_bounds__(256, 4)
void qll_kernel_fb(const float* __restrict__ x,
                   const float* __restrict__ angles,
                   float* __restrict__ out,
                   int batch)
{
    __shared__ float2 cs[DIM];
    __shared__ f32x4  stage[WAVES_PER_BLOCK][512];

    const int tid  = threadIdx.x;
    const int l    = tid & 63;
    const int wave = tid >> 6;
    const int h    = (tid >> 5) & 1;
    const int t    = tid & 31;
    const int r0   = blockIdx.x * (WAVES_PER_BLOCK * 2) + wave * 2;
    const bool active = (r0 + 2 <= batch);
    const int swz_l = l ^ ((l >> 3) & 7);

    for (int loc = tid; loc < DIM; loc += 256) {
        int j = ((loc & 31) << 5) | (loc >> 5);
        float a = angles[j];
        cs[loc] = make_float2(cosf(a), sinf(a));
    }
    __syncthreads();
    if (!active) return;

    const f32x4* gin = reinterpret_cast<const f32x4*>(x) + (size_t)r0 * 256;
#pragma unroll
    for (int m = 0; m < 8; ++m) {
        __builtin_amdgcn_global_load_lds(
            (const AS1 void*)(gin + m * 64 + swz_l),
            (AS3 void*)(&stage[wave][m * 64]), 16, 0, 0);
    }
    asm volatile("s_waitcnt vmcnt(0)" ::: "memory");
    __builtin_amdgcn_sched_barrier(0);

    float v[SEG];
#pragma unroll
    for (int e = 0; e < SEG4; ++e) {
        f32x4 q = stage[wave][h * 256 + t * 8 + (e ^ (t & 7))];
        v[4*e+0] = q.x; v[4*e+1] = q.y; v[4*e+2] = q.z; v[4*e+3] = q.w;
    }
    float v0row = __shfl(v[0], 0, LPR);
    float v1row = __shfl(v[1], 0, LPR);
    float vnext = __shfl_down(v[0], 1, LPR);

    float A = 1.f, B = 0.f;
#pragma unroll
    for (int i = 0; i < SEG - 1; ++i) {
        float2 w = cs[i * LPR + t];
        B = w.y * B + w.x * v[i + 1];
        A = w.y * A;
    }
    {
        float2 w = cs[(SEG - 1) * LPR + t];
        B = w.y * B + w.x * vnext;
        A = w.y * A;
    }
#pragma unroll
    for (int d = 1; d < LPR; d <<= 1) {
        float pa = __shfl_up(A, d, LPR);
        float pb = __shfl_up(B, d, LPR);
        if (t >= d) { B = A * pb + B; A = A * pa; }
    }
    float ea = __shfl_up(A, 1, LPR);
    float eb = __shfl_up(B, 1, LPR);
    if (t == 0) { ea = 1.f; eb = 0.f; }
    float carry = ea * v0row + eb;

    float2 w0 = cs[0];
    float out0_prov = w0.x * v0row - w0.y * v1row;

#pragma unroll
    for (int i = 0; i < SEG - 1; ++i) {
        float2 w = cs[i * LPR + t];
        float vn = v[i + 1];
        float o  = w.x * carry - w.y * vn;
        carry    = w.y * carry + w.x * vn;
        v[i] = o;
    }
    {
        float2 w  = cs[(SEG - 1) * LPR + t];
        float vn  = (t == LPR - 1) ? out0_prov : vnext;
        float o   = w.x * carry - w.y * vn;
        float nc  = w.y * carry + w.x * vn;
        v[SEG - 1] = o;
        float out0_final = __shfl(nc, LPR - 1, LPR);
        if (t == 0) v[0] = out0_final;
    }
#pragma unroll
    for (int e = 0; e < SEG4; ++e) {
        f32x4 q = { v[4*e+0], v[4*e+1], v[4*e+2], v[4*e+3] };
        stage[wave][h * 256 + t * 8 + (e ^ (t & 7))] = q;
    }
    f32x4* gout = reinterpret_cast<f32x4*>(out) + (size_t)r0 * 256;
#pragma unroll
    for (int m = 0; m < 8; ++m) {
        f32x4 q = stage[wave][m * 64 + swz_l];
        __builtin_nontemporal_store(q, gout + m * 64 + l);
    }
}

extern "C" void kernel_launch(void* const* d_in, const int* in_sizes, int n_in,
                              void* d_out, int out_size, void* d_ws, size_t ws_size,
                              hipStream_t stream) {
    const float* x      = (const float*)d_in[0];
    const float* angles = (const float*)d_in[1];
    float* outp         = (float*)d_out;

    int batch = in_sizes[0] / DIM;   // 65536

    if (ws_size >= (size_t)(DIM * sizeof(float2))) {
        float2* ws = (float2*)d_ws;
        qll_table<<<(DIM + 255) / 256, 256, 0, stream>>>(angles, ws);
        int pairs = batch / 2;                                     // 32768
        int grid  = (pairs + WAVES_PER_BLOCK - 1) / WAVES_PER_BLOCK; // 8192
        qll_kernel<<<grid, 256, 0, stream>>>(x, ws, outp, batch);
    } else {
        int rowsPerBlock = WAVES_PER_BLOCK * 2;
        int grid = (batch + rowsPerBlock - 1) / rowsPerBlock;
        qll_kernel_fb<<<grid, 256, 0, stream>>>(x, angles, outp, batch);
    }
}

// Round 10
// 92.222 us; speedup vs baseline: 3.7571x; 1.2150x over previous
//
#include <hip/hip_runtime.h>

#define DIM   1024
#define LPR   32            // lanes cooperating on one row (2 rows per wave)
#define SEG   (DIM / LPR)   // 32 floats per lane
#define SEG4  (SEG / 4)     // 8 float4 per lane
#define WAVES_PER_BLOCK 4
#define PAIRS_PER_WAVE  8   // row-pairs each wave streams through

typedef float f32x4 __attribute__((ext_vector_type(4)));
#define AS1 __attribute__((address_space(1)))
#define AS3 __attribute__((address_space(3)))

// ---------------- kernel 1: permuted cos/sin table -> d_ws ------------------
// ws[loc] = (cos a_j, sin a_j), loc = (j&31)*32 + (j>>5) (10-bit rot5), so the
// main kernel's phase read cs[i*32+t] is linear-in-t (2-way max = free).
__global__ void qll_table(const float* __restrict__ angles, float2* __restrict__ ws) {
    int j = blockIdx.x * blockDim.x + threadIdx.x;
    if (j < DIM) {
        float a = angles[j];
        ws[(j & 31) * LPR + (j >> 5)] = make_float2(cosf(a), sinf(a));
    }
}

// ---------------- main kernel ----------------------------------------------
// Row recurrence (Givens sweep): carry = value of column i entering step i.
//   out[i] = c_i*carry - s_i*v[i+1];  carry' = s_i*carry + c_i*v[i+1]
// Affine in carry -> per-lane (A,B) + width-32 shfl scan (the wave's two rows
// scan in parallel). Compute/DS body is r7's verbatim.
//
// vs r7: each wave STREAMS PAIRS_PER_WAVE row-pairs through a DOUBLE-BUFFERED
// global_load_lds pipeline (no registers hold prefetch data -> no r8 spill).
// While pair k computes from buf[k&1], pair k+1 is in flight; pair k+2 is
// issued after pair k's stores (so the DMA can't overwrite data being read).
// vmcnt retirement is in-issue-order, so counted waits isolate glds(k):
//   steady state: younger ops = stores(k-1) x8 + glds(k+1) x8 -> vmcnt(16).
__global__ __launch_bounds__(256, 2)
void qll_kernel(const float* __restrict__ x,
                const float2* __restrict__ csws,
                float* __restrict__ out,
                int batch)
{
    __shared__ float2 cs[DIM];                         // 8 KB
    __shared__ f32x4  stage[WAVES_PER_BLOCK][2][512];  // 64 KB, wave-private dbuf

    const int tid  = threadIdx.x;
    const int l    = tid & 63;        // lane in wave
    const int wave = tid >> 6;        // 0..3
    const int h    = (tid >> 5) & 1;  // which row of the pair
    const int t    = tid & 31;        // segment index within row
    const int swz_l = l ^ ((l >> 3) & 7);   // involution on f32x4 index

    const int pairBase = (blockIdx.x * WAVES_PER_BLOCK + wave) * PAIRS_PER_WAVE;
    const int pairsTot = batch >> 1;
    int np = pairsTot - pairBase;
    if (np < 0) np = 0;
    if (np > PAIRS_PER_WAVE) np = PAIRS_PER_WAVE;

    // ---- cs table glds (oldest in vmcnt order; L2-resident) ----
    const f32x4* w4 = reinterpret_cast<const f32x4*>(csws);
    f32x4* c4 = reinterpret_cast<f32x4*>(cs);
    __builtin_amdgcn_global_load_lds((const AS1 void*)(w4 + wave * 64 + l),
                                     (AS3 void*)(c4 + wave * 64), 16, 0, 0);
    __builtin_amdgcn_global_load_lds((const AS1 void*)(w4 + 256 + wave * 64 + l),
                                     (AS3 void*)(c4 + 256 + wave * 64), 16, 0, 0);

    // ---- prime the pipeline: pairs 0 and 1 ----
    const f32x4* ginb = reinterpret_cast<const f32x4*>(x);
    if (np > 0) {
        const f32x4* g = ginb + (size_t)pairBase * 512;
#pragma unroll
        for (int m = 0; m < 8; ++m)
            __builtin_amdgcn_global_load_lds((const AS1 void*)(g + m * 64 + swz_l),
                                             (AS3 void*)(&stage[wave][0][m * 64]), 16, 0, 0);
    }
    if (np > 1) {
        const f32x4* g = ginb + (size_t)(pairBase + 1) * 512;
#pragma unroll
        for (int m = 0; m < 8; ++m)
            __builtin_amdgcn_global_load_lds((const AS1 void*)(g + m * 64 + swz_l),
                                             (AS3 void*)(&stage[wave][1][m * 64]), 16, 0, 0);
    }

    // ---- wait for cs only (row glds stay in flight), raw barrier ----
    asm volatile("s_waitcnt vmcnt(16)" ::: "memory");
    __builtin_amdgcn_s_barrier();
    if (np <= 0) return;

    f32x4* goutb = reinterpret_cast<f32x4*>(out);

    for (int it = 0; it < np; ++it) {
        f32x4* buf = stage[wave][it & 1];

        // ---- counted wait: glds(it) retired (vmcnt retires in issue order) ----
        if (it == 0) {
            if (np > 1) { asm volatile("s_waitcnt vmcnt(8)"  ::: "memory"); }
            else        { asm volatile("s_waitcnt vmcnt(0)"  ::: "memory"); }
        } else if (it + 1 < np) {
            asm volatile("s_waitcnt vmcnt(16)" ::: "memory");
        } else {
            asm volatile("s_waitcnt vmcnt(8)"  ::: "memory");
        }
        __builtin_amdgcn_sched_barrier(0);

        // ---- read this lane's 32-float segment (bank-balanced b128s) ----
        float v[SEG];
#pragma unroll
        for (int e = 0; e < SEG4; ++e) {
            f32x4 q = buf[h * 256 + t * 8 + (e ^ (t & 7))];
            v[4*e+0] = q.x; v[4*e+1] = q.y; v[4*e+2] = q.z; v[4*e+3] = q.w;
        }

        // boundary exchanges (capture BEFORE phase 2 overwrites v[])
        float v0row = __shfl(v[0], 0, LPR);        // row's original column 0
        float v1row = __shfl(v[1], 0, LPR);
        float vnext = __shfl_down(v[0], 1, LPR);   // next lane's first elem

        // ---- phase 1: per-lane affine (A,B) with carry_in = 0 ----
        float A = 1.f, B = 0.f;
#pragma unroll
        for (int i = 0; i < SEG - 1; ++i) {
            float2 w = cs[i * LPR + t];
            B = w.y * B + w.x * v[i + 1];
            A = w.y * A;
        }
        {   // last step of segment consumes the boundary element
            float2 w = cs[(SEG - 1) * LPR + t];
            B = w.y * B + w.x * vnext;   // lane 31: finite garbage, unused
            A = w.y * A;
        }

        // ---- inclusive affine scan across 32 lanes (both rows in parallel) ----
#pragma unroll
        for (int d = 1; d < LPR; d <<= 1) {
            float pa = __shfl_up(A, d, LPR);
            float pb = __shfl_up(B, d, LPR);
            if (t >= d) { B = A * pb + B; A = A * pa; }
        }
        // exclusive prefix -> carry entering this lane's segment
        float ea = __shfl_up(A, 1, LPR);
        float eb = __shfl_up(B, 1, LPR);
        if (t == 0) { ea = 1.f; eb = 0.f; }
        float carry = ea * v0row + eb;

        // provisional out[0] (result of step 0), consumed by wrap step 1023
        float2 w0 = cs[0];
        float out0_prov = w0.x * v0row - w0.y * v1row;

        // ---- phase 2: replay with true carry, outputs into v[] ----
#pragma unroll
        for (int i = 0; i < SEG - 1; ++i) {
            float2 w = cs[i * LPR + t];
            float vn = v[i + 1];
            float o  = w.x * carry - w.y * vn;
            carry    = w.y * carry + w.x * vn;
            v[i] = o;
        }
        {   // last step; lane 31 executes the wrap step 1023 against out[0]
            float2 w  = cs[(SEG - 1) * LPR + t];
            float vn  = (t == LPR - 1) ? out0_prov : vnext;
            float o   = w.x * carry - w.y * vn;
            float nc  = w.y * carry + w.x * vn;
            v[SEG - 1] = o;
            float out0_final = __shfl(nc, LPR - 1, LPR);  // lane 31 -> all
            if (t == 0) v[0] = out0_final;
        }

        // ---- out-stage into buf (same-wave DS pipe in-order), then
        //      coalesced nontemporal stores ----
#pragma unroll
        for (int e = 0; e < SEG4; ++e) {
            f32x4 q = { v[4*e+0], v[4*e+1], v[4*e+2], v[4*e+3] };
            buf[h * 256 + t * 8 + (e ^ (t & 7))] = q;
        }
        f32x4* gout = goutb + (size_t)(pairBase + it) * 512;
#pragma unroll
        for (int m = 0; m < 8; ++m) {
            f32x4 q = buf[m * 64 + swz_l];
            __builtin_nontemporal_store(q, gout + m * 64 + l);
        }

        // ---- issue glds for pair it+2 into THIS buffer, strictly after the
        //      stores' ds_reads (sched_barrier pins the boundary) ----
        __builtin_amdgcn_sched_barrier(0);
        if (it + 2 < np) {
            const f32x4* g = ginb + (size_t)(pairBase + it + 2) * 512;
#pragma unroll
            for (int m = 0; m < 8; ++m)
                __builtin_amdgcn_global_load_lds((const AS1 void*)(g + m * 64 + swz_l),
                                                 (AS3 void*)(&buf[m * 64]), 16, 0, 0);
        }
    }
}

// ---------------- fallback (ws too small): r6-style self-contained ---------
__global__ __launch_bounds__(256, 4)
void qll_kernel_fb(const float* __restrict__ x,
                   const float* __restrict__ angles,
                   float* __restrict__ out,
                   int batch)
{
    __shared__ float2 cs[DIM];
    __shared__ f32x4  stage[WAVES_PER_BLOCK][512];

    const int tid  = threadIdx.x;
    const int l    = tid & 63;
    const int wave = tid >> 6;
    const int h    = (tid >> 5) & 1;
    const int t    = tid & 31;
    const int r0   = blockIdx.x * (WAVES_PER_BLOCK * 2) + wave * 2;
    const bool active = (r0 + 2 <= batch);
    const int swz_l = l ^ ((l >> 3) & 7);

    for (int loc = tid; loc < DIM; loc += 256) {
        int j = ((loc & 31) << 5) | (loc >> 5);
        float a = angles[j];
        cs[loc] = make_float2(cosf(a), sinf(a));
    }
    __syncthreads();
    if (!active) return;

    const f32x4* gin = reinterpret_cast<const f32x4*>(x) + (size_t)r0 * 256;
#pragma unroll
    for (int m = 0; m < 8; ++m) {
        __builtin_amdgcn_global_load_lds(
            (const AS1 void*)(gin + m * 64 + swz_l),
            (AS3 void*)(&stage[wave][m * 64]), 16, 0, 0);
    }
    asm volatile("s_waitcnt vmcnt(0)" ::: "memory");
    __builtin_amdgcn_sched_barrier(0);

    float v[SEG];
#pragma unroll
    for (int e = 0; e < SEG4; ++e) {
        f32x4 q = stage[wave][h * 256 + t * 8 + (e ^ (t & 7))];
        v[4*e+0] = q.x; v[4*e+1] = q.y; v[4*e+2] = q.z; v[4*e+3] = q.w;
    }
    float v0row = __shfl(v[0], 0, LPR);
    float v1row = __shfl(v[1], 0, LPR);
    float vnext = __shfl_down(v[0], 1, LPR);

    float A = 1.f, B = 0.f;
#pragma unroll
    for (int i = 0; i < SEG - 1; ++i) {
        float2 w = cs[i * LPR + t];
        B = w.y * B + w.x * v[i + 1];
        A = w.y * A;
    }
    {
        float2 w = cs[(SEG - 1) * LPR + t];
        B = w.y * B + w.x * vnext;
        A = w.y * A;
    }
#pragma unroll
    for (int d = 1; d < LPR; d <<= 1) {
        float pa = __shfl_up(A, d, LPR);
        float pb = __shfl_up(B, d, LPR);
        if (t >= d) { B = A * pb + B; A = A * pa; }
    }
    float ea = __shfl_up(A, 1, LPR);
    float eb = __shfl_up(B, 1, LPR);
    if (t == 0) { ea = 1.f; eb = 0.f; }
    float carry = ea * v0row + eb;

    float2 w0 = cs[0];
    float out0_prov = w0.x * v0row - w0.y * v1row;

#pragma unroll
    for (int i = 0; i < SEG - 1; ++i) {
        float2 w = cs[i * LPR + t];
        float vn = v[i + 1];
        float o  = w.x * carry - w.y * vn;
        carry    = w.y * carry + w.x * vn;
        v[i] = o;
    }
    {
        float2 w  = cs[(SEG - 1) * LPR + t];
        float vn  = (t == LPR - 1) ? out0_prov : vnext;
        float o   = w.x * carry - w.y * vn;
        float nc  = w.y * carry + w.x * vn;
        v[SEG - 1] = o;
        float out0_final = __shfl(nc, LPR - 1, LPR);
        if (t == 0) v[0] = out0_final;
    }
#pragma unroll
    for (int e = 0; e < SEG4; ++e) {
        f32x4 q = { v[4*e+0], v[4*e+1], v[4*e+2], v[4*e+3] };
        stage[wave][h * 256 + t * 8 + (e ^ (t & 7))] = q;
    }
    f32x4* gout = reinterpret_cast<f32x4*>(out) + (size_t)r0 * 256;
#pragma unroll
    for (int m = 0; m < 8; ++m) {
        f32x4 q = stage[wave][m * 64 + swz_l];
        __builtin_nontemporal_store(q, gout + m * 64 + l);
    }
}

extern "C" void kernel_launch(void* const* d_in, const int* in_sizes, int n_in,
                              void* d_out, int out_size, void* d_ws, size_t ws_size,
                              hipStream_t stream) {
    const float* x      = (const float*)d_in[0];
    const float* angles = (const float*)d_in[1];
    float* outp         = (float*)d_out;

    int batch = in_sizes[0] / DIM;   // 65536

    if (ws_size >= (size_t)(DIM * sizeof(float2))) {
        float2* ws = (float2*)d_ws;
        qll_table<<<(DIM + 255) / 256, 256, 0, stream>>>(angles, ws);
        int pairs = batch / 2;                                   // 32768
        int perBlock = WAVES_PER_BLOCK * PAIRS_PER_WAVE;         // 32
        int grid = (pairs + perBlock - 1) / perBlock;            // 1024
        qll_kernel<<<grid, 256, 0, stream>>>(x, ws, outp, batch);
    } else {
        int rowsPerBlock = WAVES_PER_BLOCK * 2;
        int grid = (batch + rowsPerBlock - 1) / rowsPerBlock;
        qll_kernel_fb<<<grid, 256, 0, stream>>>(x, angles, outp, batch);
    }
}